// Round 1
// baseline (32511.111 us; speedup 1.0000x reference)
//
#include <hip/hip_runtime.h>
#include <hip/hip_cooperative_groups.h>
#include <math.h>

namespace cg = cooperative_groups;

static constexpr int Bc   = 64;    // batch
static constexpr int Tc   = 512;   // seq len
static constexpr int EMBc = 512;
static constexpr int HIDc = 512;
static constexpr int Kc   = 1024;  // combined input length
static constexpr int CH   = 128;   // k-chunk staged in LDS
static constexpr int NWGc = 256;   // 128 layer-0 WGs + 128 layer-1 WGs
static constexpr int THR  = 256;

// Persistent cooperative kernel. WG wg<128 owns h-indices [4*wg,4*wg+4) of
// layer 0; wg>=128 similarly for layer 1. Diagonal pipeline: at wave w,
// layer0 computes t=w, layer1 computes t=w-1. One grid.sync per wave.
// h state in ws, transposed [h][b], double-buffered by t parity.
// c state in thread-private registers (thread (b=tid&63, h_local=tid>>6)).
__global__ __launch_bounds__(THR, 1)
void lstm_persistent(const int* __restrict__ xp,
                     const float* __restrict__ emb,
                     const float* __restrict__ W0,
                     const float* __restrict__ b0,
                     const float* __restrict__ W1,
                     const float* __restrict__ b1,
                     const float* __restrict__ fcw,
                     const float* __restrict__ fcb,
                     float* __restrict__ out,
                     float* __restrict__ ws)
{
    cg::grid_group grid = cg::this_grid();

    float* h0g = ws;                      // [2][HID][B]
    float* h1g = ws + 2 * HIDc * Bc;      // [2][HID][B]

    const int tid    = threadIdx.x;
    const int wg     = blockIdx.x;
    const bool is_l0 = (wg < 128);
    const int hw     = (is_l0 ? wg : wg - 128) * 4;   // base h index owned

    const float* Wb = is_l0 ? W0 : W1;
    const float* bb = is_l0 ? b0 : b1;

    __shared__ float comb[CH][Bc];   // staged combined-input chunk, [k][b]
    __shared__ float pre[4][4][Bc];  // gate preacts [gate][h_local][b]

    // zero-init all 4 h buffers (ws is poisoned; must be deterministic)
    for (int i = wg * THR + tid; i < 4 * HIDc * Bc; i += NWGc * THR)
        ws[i] = 0.0f;

    const int b_ = tid & 63;
    const int wv = __builtin_amdgcn_readfirstlane(tid >> 6); // wave id = gate id (compute) = h_local (update)

    // this wave's 4 weight rows: gate wv, h = hw..hw+3. Wave-uniform -> s_load.
    const float* Wr0 = Wb + (size_t)(wv * HIDc + hw + 0) * Kc;
    const float* Wr1 = Wb + (size_t)(wv * HIDc + hw + 1) * Kc;
    const float* Wr2 = Wb + (size_t)(wv * HIDc + hw + 2) * Kc;
    const float* Wr3 = Wb + (size_t)(wv * HIDc + hw + 3) * Kc;

    float cpriv = 0.0f;   // c[b_][hw+wv] for this layer

    grid.sync();          // zero-init visible grid-wide

    for (int w = 0; w <= Tc; ++w) {
        const bool active = is_l0 ? (w < Tc) : (w >= 1);
        if (active) {
            // buffers: h0(t) written to parity t; h1(t) written to parity t
            const float* h0prev = h0g + ((w - 1) & 1) * HIDc * Bc; // h0(w-1)
            const float* h1prev = h1g + (w & 1) * HIDc * Bc;       // h1(w-2)
            float* hdst = is_l0 ? (h0g + (w & 1) * HIDc * Bc)       // h0(w)
                                : (h1g + ((w - 1) & 1) * HIDc * Bc);// h1(w-1)

            int tok = 0;
            if (is_l0) tok = xp[b_ * Tc + w];   // token for t = w

            float a0 = 0.f, a1 = 0.f, a2 = 0.f, a3 = 0.f;

            for (int kc = 0; kc < Kc; kc += CH) {
                __syncthreads();   // previous chunk's reads done
                if (is_l0 && kc < EMBc) {
                    // gather embedding row (padding_idx 0 -> zeros), transpose into LDS
                    const float* er = emb + (size_t)tok * EMBc;
                    #pragma unroll
                    for (int p = 0; p < CH / 16; ++p) {
                        const int kl = p * 16 + wv * 4;
                        float4 v = make_float4(0.f, 0.f, 0.f, 0.f);
                        if (tok != 0)
                            v = *reinterpret_cast<const float4*>(er + kc + kl);
                        comb[kl + 0][b_] = v.x;
                        comb[kl + 1][b_] = v.y;
                        comb[kl + 2][b_] = v.z;
                        comb[kl + 3][b_] = v.w;
                    }
                } else {
                    // straight copy from transposed h buffers
                    const float* src;
                    if (is_l0)           src = h0prev + (kc - EMBc) * Bc;
                    else if (kc < HIDc)  src = h0prev + kc * Bc;
                    else                 src = h1prev + (kc - HIDc) * Bc;
                    const float4* s4 = reinterpret_cast<const float4*>(src);
                    float4* d4 = reinterpret_cast<float4*>(&comb[0][0]);
                    #pragma unroll
                    for (int p = 0; p < (CH * Bc / 4) / THR; ++p)
                        d4[p * THR + tid] = s4[p * THR + tid];
                }
                __syncthreads();

                #pragma unroll 8
                for (int k = 0; k < CH; ++k) {
                    const float xv = comb[k][b_];   // conflict-free: lane = b
                    a0 = fmaf(xv, Wr0[kc + k], a0); // W via scalar loads
                    a1 = fmaf(xv, Wr1[kc + k], a1);
                    a2 = fmaf(xv, Wr2[kc + k], a2);
                    a3 = fmaf(xv, Wr3[kc + k], a3);
                }
            }

            // publish preacts (+bias), then cell update
            pre[wv][0][b_] = a0 + bb[wv * HIDc + hw + 0];
            pre[wv][1][b_] = a1 + bb[wv * HIDc + hw + 1];
            pre[wv][2][b_] = a2 + bb[wv * HIDc + hw + 2];
            pre[wv][3][b_] = a3 + bb[wv * HIDc + hw + 3];
            __syncthreads();

            {
                // gate order (i, f, o, c); act: sigmoid/sigmoid/sigmoid/relu
                const float ig = 1.f / (1.f + expf(-pre[0][wv][b_]));
                const float fg = 1.f / (1.f + expf(-pre[1][wv][b_]));
                const float og = 1.f / (1.f + expf(-pre[2][wv][b_]));
                const float gg = fmaxf(pre[3][wv][b_], 0.f);
                cpriv = fg * cpriv + ig * gg;
                const float hn = og * fmaxf(cpriv, 0.f);
                hdst[(hw + wv) * Bc + b_] = hn;
            }
        }
        grid.sync();
    }

    // final FC + sigmoid on h1(T-1) (parity (T-1)&1 = 1)
    if (wg == 0 && tid < Bc) {
        const float* h1f = h1g + ((Tc - 1) & 1) * HIDc * Bc;
        float s = fcb[0];
        for (int h = 0; h < HIDc; ++h)
            s = fmaf(h1f[h * Bc + tid], fcw[h], s);
        out[tid] = 1.f / (1.f + expf(-s));
    }
}

extern "C" void kernel_launch(void* const* d_in, const int* in_sizes, int n_in,
                              void* d_out, int out_size, void* d_ws, size_t ws_size,
                              hipStream_t stream) {
    const int*   xp  = (const int*)d_in[0];
    const float* emb = (const float*)d_in[1];
    const float* W0  = (const float*)d_in[2];
    const float* b0  = (const float*)d_in[3];
    const float* W1  = (const float*)d_in[4];
    const float* b1  = (const float*)d_in[5];
    const float* fcw = (const float*)d_in[6];
    const float* fcb = (const float*)d_in[7];
    float* out = (float*)d_out;
    float* ws  = (float*)d_ws;

    void* args[] = { (void*)&xp, (void*)&emb, (void*)&W0, (void*)&b0,
                     (void*)&W1, (void*)&b1, (void*)&fcw, (void*)&fcb,
                     (void*)&out, (void*)&ws };
    hipLaunchCooperativeKernel((void*)lstm_persistent, dim3(NWGc), dim3(THR),
                               args, 0, stream);
}